// Round 1
// baseline (300.621 us; speedup 1.0000x reference)
//
#include <hip/hip_runtime.h>
#include <math.h>

#define T_LEN 1024
#define PRED_LEN 256
#define OUT_T (T_LEN + PRED_LEN)
#define DM 256
#define KSEL 32

static __device__ __constant__ double TWO_PI_D = 6.283185307179586476925286766559;

// ---------------- Kernel T: cos/sin tables (fp64 -> fp32), 1 block ----------------
__global__ void fl_table_kernel(float* __restrict__ ctab, float* __restrict__ stab) {
    int tid = threadIdx.x;
    for (int q = 0; q < 4; ++q) {
        int j = tid + (q << 8);
        double ang = (double)j * (TWO_PI_D / 1024.0);
        ctab[j] = (float)cos(ang);
        stab[j] = (float)sin(ang);
    }
}

// ---------------- Kernel A: fp64 FFT + top-32 per (b,d) column ----------------
// grid = 2048 blocks (8*256), block = 256 threads
__global__ void __launch_bounds__(256)
fl_fft_topk_kernel(const float* __restrict__ x,
                   int* __restrict__ Mi, float* __restrict__ Ac, float* __restrict__ Bc) {
    __shared__ double re[1024], im[1024];
    __shared__ double wre[512], wim[512];
    __shared__ double mg[512];
    __shared__ double wval[4];
    __shared__ int widx[4];
    __shared__ int selM[KSEL];
    __shared__ float selA[KSEL], selB[KSEL];

    const int tid = threadIdx.x;
    const int sig = blockIdx.x;          // 0..2047
    const int b = sig >> 8;
    const int d = sig & 255;

    // load column (bit-reversed positions), imag = 0
    for (int q = 0; q < 4; ++q) {
        int t = tid + (q << 8);
        int r = (int)(__brev((unsigned)t) >> 22);
        re[r] = (double)x[((b << 10) + t) * DM + d];
        im[r] = 0.0;
    }
    // twiddle table w[k] = exp(-2*pi*i*k/1024), k=0..511
    for (int q = 0; q < 2; ++q) {
        int k = tid + (q << 8);
        double ang = (double)k * (TWO_PI_D / 1024.0);
        wre[k] = cos(ang);
        wim[k] = -sin(ang);
    }
    __syncthreads();

    // radix-2 DIT, 10 stages, 512 butterflies/stage, 2 per thread
    for (int s = 0; s < 10; ++s) {
        const int h = 1 << s;
        for (int q = 0; q < 2; ++q) {
            int j = tid + (q << 8);                  // 0..511
            int p = j & (h - 1);
            int i0 = ((j >> s) << (s + 1)) | p;
            int i1 = i0 + h;
            int twi = p << (9 - s);
            double wr = wre[twi], wi = wim[twi];
            double ar = re[i0], ai = im[i0];
            double br = re[i1], bi = im[i1];
            double tr = wr * br - wi * bi;
            double ti = wr * bi + wi * br;
            re[i0] = ar + tr; im[i0] = ai + ti;
            re[i1] = ar - tr; im[i1] = ai - ti;
        }
        __syncthreads();
    }

    // magnitudes^2 for m = 0..511 (m=0 excluded; m=512 Nyquist excluded by range)
    for (int q = 0; q < 2; ++q) {
        int m = tid + (q << 8);
        mg[m] = re[m] * re[m] + im[m] * im[m];
    }
    __syncthreads();
    if (tid == 0) mg[0] = -1.0;
    __syncthreads();

    // top-32 by repeated argmax; tie-break lower index (jax top_k semantics)
    const int lane = tid & 63;
    const int wid = tid >> 6;
    for (int it = 0; it < KSEL; ++it) {
        double v0 = mg[tid], v1 = mg[tid + 256];
        double bv; int bi;
        if (v1 > v0) { bv = v1; bi = tid + 256; } else { bv = v0; bi = tid; }
        // wave64 butterfly argmax
        for (int off = 32; off > 0; off >>= 1) {
            double ov = __shfl_xor(bv, off);
            int oi = __shfl_xor(bi, off);
            if (ov > bv || (ov == bv && oi < bi)) { bv = ov; bi = oi; }
        }
        if (lane == 0) { wval[wid] = bv; widx[wid] = bi; }
        __syncthreads();
        if (tid == 0) {
            double fv = wval[0]; int fi = widx[0];
            for (int w = 1; w < 4; ++w) {
                if (wval[w] > fv || (wval[w] == fv && widx[w] < fi)) { fv = wval[w]; fi = widx[w]; }
            }
            selM[it] = fi;
            selA[it] = (float)( 2.0 * re[fi] / (double)T_LEN);
            selB[it] = (float)(-2.0 * im[fi] / (double)T_LEN);
            mg[fi] = -1.0;
        }
        __syncthreads();
    }

    if (tid < KSEL) {
        int base = sig * KSEL + tid;
        Mi[base] = selM[tid];
        Ac[base] = selA[tid];
        Bc[base] = selB[tid];
    }
}

// ---------------- Kernel B: synthesis ----------------
// grid = (1280, 8), block = 256 (thread = d)
__global__ void __launch_bounds__(256)
fl_synth_kernel(const int* __restrict__ Mi, const float* __restrict__ Ac,
                const float* __restrict__ Bc, const float* __restrict__ gct,
                const float* __restrict__ gst, float* __restrict__ out) {
    __shared__ float ctab[1024], stab[1024];
    const int tid = threadIdx.x;
    for (int q = 0; q < 4; ++q) {
        int j = tid + (q << 8);
        ctab[j] = gct[j];
        stab[j] = gst[j];
    }
    __syncthreads();

    const int tv = blockIdx.x;
    const int b  = blockIdx.y;
    const int base = (((b << 8) + tid) << 5);  // (b*256+d)*32

    const int4*   Mi4 = reinterpret_cast<const int4*>(Mi + base);
    const float4* Ac4 = reinterpret_cast<const float4*>(Ac + base);
    const float4* Bc4 = reinterpret_cast<const float4*>(Bc + base);

    float s = 0.0f;
#pragma unroll
    for (int k8 = 0; k8 < 8; ++k8) {
        int4   m4 = Mi4[k8];
        float4 a4 = Ac4[k8];
        float4 b4 = Bc4[k8];
        int j0 = (m4.x * tv) & 1023;
        int j1 = (m4.y * tv) & 1023;
        int j2 = (m4.z * tv) & 1023;
        int j3 = (m4.w * tv) & 1023;
        s += a4.x * ctab[j0] + b4.x * stab[j0];
        s += a4.y * ctab[j1] + b4.y * stab[j1];
        s += a4.z * ctab[j2] + b4.z * stab[j2];
        s += a4.w * ctab[j3] + b4.w * stab[j3];
    }
    out[(b * OUT_T + tv) * DM + tid] = s;
}

extern "C" void kernel_launch(void* const* d_in, const int* in_sizes, int n_in,
                              void* d_out, int out_size, void* d_ws, size_t ws_size,
                              hipStream_t stream) {
    const float* x = (const float*)d_in[0];
    float* out = (float*)d_out;

    char* w = (char*)d_ws;
    const size_t NSIG = 8 * 256;
    const size_t coefBytes = NSIG * KSEL * sizeof(int);  // 256 KiB each
    int*   Mi   = (int*)(w);
    float* Ac   = (float*)(w + coefBytes);
    float* Bc   = (float*)(w + 2 * coefBytes);
    float* ctab = (float*)(w + 3 * coefBytes);
    float* stab = (float*)(w + 3 * coefBytes + 1024 * sizeof(float));

    hipLaunchKernelGGL(fl_table_kernel, dim3(1), dim3(256), 0, stream, ctab, stab);
    hipLaunchKernelGGL(fl_fft_topk_kernel, dim3(2048), dim3(256), 0, stream,
                       x, Mi, Ac, Bc);
    hipLaunchKernelGGL(fl_synth_kernel, dim3(OUT_T, 8), dim3(256), 0, stream,
                       Mi, Ac, Bc, ctab, stab, out);
}

// Round 2
// 131.404 us; speedup vs baseline: 2.2878x; 2.2878x over previous
//
#include <hip/hip_runtime.h>
#include <math.h>

#define T_LEN 1024
#define PRED_LEN 256
#define OUT_T (T_LEN + PRED_LEN)
#define DM 256
#define KSEL 32
#define TVC 16

static __device__ __constant__ double TWO_PI_D = 6.283185307179586476925286766559;
#define TWO_PI_F 6.2831853071795864769f
#define INV1024  0.0009765625f

// ---------------- Kernel A: fp64 FFT + top-32 per (b,d) column ----------------
// grid = 2048 blocks (8*256), block = 256 threads
__global__ void __launch_bounds__(256)
fl_fft_topk_kernel(const float* __restrict__ x,
                   int* __restrict__ Mi, float* __restrict__ Ac, float* __restrict__ Bc) {
    __shared__ double re[1024], im[1024];
    __shared__ double wre[512], wim[512];
    __shared__ double mg[512];
    __shared__ double wval[4];
    __shared__ int widx[4];
    __shared__ int selM[KSEL];
    __shared__ float selA[KSEL], selB[KSEL];

    const int tid = threadIdx.x;
    const int sig = blockIdx.x;          // 0..2047
    const int b = sig >> 8;
    const int d = sig & 255;

    // load column (bit-reversed positions), imag = 0
    for (int q = 0; q < 4; ++q) {
        int t = tid + (q << 8);
        int r = (int)(__brev((unsigned)t) >> 22);
        re[r] = (double)x[((b << 10) + t) * DM + d];
        im[r] = 0.0;
    }
    // twiddle table w[k] = exp(-2*pi*i*k/1024), k=0..511
    for (int q = 0; q < 2; ++q) {
        int k = tid + (q << 8);
        double ang = (double)k * (TWO_PI_D / 1024.0);
        wre[k] = cos(ang);
        wim[k] = -sin(ang);
    }
    __syncthreads();

    // radix-2 DIT, 10 stages, 512 butterflies/stage, 2 per thread
    for (int s = 0; s < 10; ++s) {
        const int h = 1 << s;
        for (int q = 0; q < 2; ++q) {
            int j = tid + (q << 8);                  // 0..511
            int p = j & (h - 1);
            int i0 = ((j >> s) << (s + 1)) | p;
            int i1 = i0 + h;
            int twi = p << (9 - s);
            double wr = wre[twi], wi = wim[twi];
            double ar = re[i0], ai = im[i0];
            double br = re[i1], bi = im[i1];
            double tr = wr * br - wi * bi;
            double ti = wr * bi + wi * br;
            re[i0] = ar + tr; im[i0] = ai + ti;
            re[i1] = ar - tr; im[i1] = ai - ti;
        }
        __syncthreads();
    }

    // magnitudes^2 for m = 0..511 (m=0 excluded; m=512 Nyquist excluded by range)
    for (int q = 0; q < 2; ++q) {
        int m = tid + (q << 8);
        mg[m] = re[m] * re[m] + im[m] * im[m];
    }
    __syncthreads();
    if (tid == 0) mg[0] = -1.0;
    __syncthreads();

    // top-32 by repeated argmax; tie-break lower index (jax top_k semantics)
    const int lane = tid & 63;
    const int wid = tid >> 6;
    for (int it = 0; it < KSEL; ++it) {
        double v0 = mg[tid], v1 = mg[tid + 256];
        double bv; int bi;
        if (v1 > v0) { bv = v1; bi = tid + 256; } else { bv = v0; bi = tid; }
        // wave64 butterfly argmax
        for (int off = 32; off > 0; off >>= 1) {
            double ov = __shfl_xor(bv, off);
            int oi = __shfl_xor(bi, off);
            if (ov > bv || (ov == bv && oi < bi)) { bv = ov; bi = oi; }
        }
        if (lane == 0) { wval[wid] = bv; widx[wid] = bi; }
        __syncthreads();
        if (tid == 0) {
            double fv = wval[0]; int fi = widx[0];
            for (int w = 1; w < 4; ++w) {
                if (wval[w] > fv || (wval[w] == fv && widx[w] < fi)) { fv = wval[w]; fi = widx[w]; }
            }
            selM[it] = fi;
            selA[it] = (float)( 2.0 * re[fi] / (double)T_LEN);
            selB[it] = (float)(-2.0 * im[fi] / (double)T_LEN);
            mg[fi] = -1.0;
        }
        __syncthreads();
    }

    if (tid < KSEL) {
        int base = sig * KSEL + tid;
        Mi[base] = selM[tid];
        Ac[base] = selA[tid];
        Bc[base] = selB[tid];
    }
}

// ---------------- Kernel B: synthesis, register-resident trig ----------------
// grid = (OUT_T/TVC, 8), block = 256 (thread = d); no LDS at all.
__global__ void __launch_bounds__(256)
fl_synth_kernel(const int* __restrict__ Mi, const float* __restrict__ Ac,
                const float* __restrict__ Bc, float* __restrict__ out) {
    const int tid = threadIdx.x;
    const int b   = blockIdx.y;
    const int tv0 = blockIdx.x * TVC;
    const int base = (((b << 8) + tid) << 5);  // (b*256+d)*32

    const int4*   Mi4 = reinterpret_cast<const int4*>(Mi + base);
    const float4* Ac4 = reinterpret_cast<const float4*>(Ac + base);
    const float4* Bc4 = reinterpret_cast<const float4*>(Bc + base);

    float acc[TVC];
#pragma unroll
    for (int i = 0; i < TVC; ++i) acc[i] = 0.0f;

    for (int k8 = 0; k8 < 8; ++k8) {
        int4   m4 = Mi4[k8];
        float4 a4 = Ac4[k8];
        float4 b4 = Bc4[k8];
        int   mm[4] = {m4.x, m4.y, m4.z, m4.w};
        float AA[4] = {a4.x, a4.y, a4.z, a4.w};
        float BB[4] = {b4.x, b4.y, b4.z, b4.w};
        float c[4], s[4], cw[4], sw[4];
#pragma unroll
        for (int u = 0; u < 4; ++u) {
            float f0 = (float)((mm[u] * tv0) & 1023) * INV1024;   // phase in revolutions, [0,1)
            float fw = (float)mm[u] * INV1024;                    // step in revolutions, [0,0.5)
            c[u]  = __cosf(f0 * TWO_PI_F);
            s[u]  = __sinf(f0 * TWO_PI_F);
            cw[u] = __cosf(fw * TWO_PI_F);
            sw[u] = __sinf(fw * TWO_PI_F);
        }
#pragma unroll
        for (int i = 0; i < TVC; ++i) {
#pragma unroll
            for (int u = 0; u < 4; ++u) {
                acc[i] = fmaf(AA[u], c[u], fmaf(BB[u], s[u], acc[i]));
                float cn = fmaf(c[u], cw[u], -(s[u] * sw[u]));
                float sn = fmaf(s[u], cw[u],  (c[u] * sw[u]));
                c[u] = cn; s[u] = sn;
            }
        }
    }

    float* op = out + ((size_t)b * OUT_T + tv0) * DM + tid;
#pragma unroll
    for (int i = 0; i < TVC; ++i) {
        op[i * DM] = acc[i];
    }
}

extern "C" void kernel_launch(void* const* d_in, const int* in_sizes, int n_in,
                              void* d_out, int out_size, void* d_ws, size_t ws_size,
                              hipStream_t stream) {
    const float* x = (const float*)d_in[0];
    float* out = (float*)d_out;

    char* w = (char*)d_ws;
    const size_t NSIG = 8 * 256;
    const size_t coefBytes = NSIG * KSEL * sizeof(int);  // 256 KiB each
    int*   Mi   = (int*)(w);
    float* Ac   = (float*)(w + coefBytes);
    float* Bc   = (float*)(w + 2 * coefBytes);

    hipLaunchKernelGGL(fl_fft_topk_kernel, dim3(2048), dim3(256), 0, stream,
                       x, Mi, Ac, Bc);
    hipLaunchKernelGGL(fl_synth_kernel, dim3(OUT_T / TVC, 8), dim3(256), 0, stream,
                       Mi, Ac, Bc, out);
}

// Round 3
// 87.990 us; speedup vs baseline: 3.4165x; 1.4934x over previous
//
#include <hip/hip_runtime.h>
#include <math.h>

#define T_LEN 1024
#define PRED_LEN 256
#define OUT_T (T_LEN + PRED_LEN)
#define DM 256
#define KSEL 32
#define TVC 16

static __device__ __constant__ double TWO_PI_D = 6.283185307179586476925286766559;
#define TWO_PI_F 6.2831853071795864769f
#define INV1024  0.0009765625f

// pad every 16 doubles by 1 to break power-of-2 bank strides
#define PADI(i) ((i) + ((i) >> 4))

// ---------------- Kernel A: fp64 FFT + top-32 per (b,d) column ----------------
// grid = 2048 blocks (8*256), block = 256 threads
__global__ void __launch_bounds__(256)
fl_fft_topk_kernel(const float* __restrict__ x,
                   int* __restrict__ Mi, float* __restrict__ Ac, float* __restrict__ Bc) {
    __shared__ double re[1088], im[1088];     // PADI(1023)=1086
    __shared__ double wre[544], wim[544];     // PADI(511)=542

    const int tid = threadIdx.x;
    // XCD-chunked swizzle: XCD k gets sig in [k*256, (k+1)*256) = one full batch b
    const int bid = blockIdx.x;
    const int sig = ((bid & 7) << 8) | (bid >> 3);   // bijective over 2048
    const int b = sig >> 8;
    const int d = sig & 255;

    // load column (bit-reversed positions), imag = 0
    for (int q = 0; q < 4; ++q) {
        int t = tid + (q << 8);
        int r = (int)(__brev((unsigned)t) >> 22);
        re[PADI(r)] = (double)x[((b << 10) + t) * DM + d];
        im[PADI(r)] = 0.0;
    }
    // twiddle table w[k] = exp(-2*pi*i*k/1024), k=0..511
    for (int q = 0; q < 2; ++q) {
        int k = tid + (q << 8);
        double ang = (double)k * (TWO_PI_D / 1024.0);
        wre[PADI(k)] = cos(ang);
        wim[PADI(k)] = -sin(ang);
    }
    __syncthreads();

    // radix-2 DIT, 10 stages, 512 butterflies/stage, 2 per thread
    for (int s = 0; s < 10; ++s) {
        const int h = 1 << s;
        for (int q = 0; q < 2; ++q) {
            int j = tid + (q << 8);                  // 0..511
            int p = j & (h - 1);
            int i0 = ((j >> s) << (s + 1)) | p;
            int i1 = i0 + h;
            int twi = p << (9 - s);
            double wr = wre[PADI(twi)], wi = wim[PADI(twi)];
            int p0 = PADI(i0), p1 = PADI(i1);
            double ar = re[p0], ai = im[p0];
            double br = re[p1], bi = im[p1];
            double tr = wr * br - wi * bi;
            double ti = wr * bi + wi * br;
            re[p0] = ar + tr; im[p0] = ai + ti;
            re[p1] = ar - tr; im[p1] = ai - ti;
        }
        __syncthreads();
    }

    // waves 1..3 are done; wave 0 does the whole top-k in registers+shuffles.
    if (tid >= 64) return;

    // lane 'tid' owns magnitudes for m = q*64 + tid, q = 0..7  (m in 0..511)
    double v[8];
#pragma unroll
    for (int q = 0; q < 8; ++q) {
        int m = (q << 6) | tid;
        int pm = PADI(m);
        double rr = re[pm], ii = im[pm];
        v[q] = rr * rr + ii * ii;
    }
    if (tid == 0) v[0] = -1.0;   // exclude m=0 (LOW_FREQ); m=512 excluded by range

    int mysel = 0;
    for (int r = 0; r < KSEL; ++r) {
        // local argmax over 8 slots (tie -> lower q -> lower m)
        double bv = v[0]; int bq = 0;
#pragma unroll
        for (int q = 1; q < 8; ++q) {
            if (v[q] > bv) { bv = v[q]; bq = q; }
        }
        int bi = (bq << 6) | tid;
        // 64-lane butterfly all-reduce argmax (tie -> lower m)
#pragma unroll
        for (int off = 1; off < 64; off <<= 1) {
            double ov = __shfl_xor(bv, off);
            int    oi = __shfl_xor(bi, off);
            if (ov > bv || (ov == bv && oi < bi)) { bv = ov; bi = oi; }
        }
        if (tid == r) mysel = bi;            // lane r records round-r winner
        if (tid == (bi & 63)) {              // owner removes it
            int wq = bi >> 6;
#pragma unroll
            for (int q = 0; q < 8; ++q) if (q == wq) v[q] = -1.0;
        }
    }

    if (tid < KSEL) {
        int m = mysel;
        int pm = PADI(m);
        double rr = re[pm], ii = im[pm];
        int basei = sig * KSEL + tid;
        Mi[basei] = m;
        Ac[basei] = (float)( 2.0 * rr / (double)T_LEN);
        Bc[basei] = (float)(-2.0 * ii / (double)T_LEN);
    }
}

// ---------------- Kernel B: synthesis, register-resident trig ----------------
// grid = (OUT_T/TVC, 8), block = 256 (thread = d); no LDS at all.
__global__ void __launch_bounds__(256)
fl_synth_kernel(const int* __restrict__ Mi, const float* __restrict__ Ac,
                const float* __restrict__ Bc, float* __restrict__ out) {
    const int tid = threadIdx.x;
    const int b   = blockIdx.y;
    const int tv0 = blockIdx.x * TVC;
    const int base = (((b << 8) + tid) << 5);  // (b*256+d)*32

    const int4*   Mi4 = reinterpret_cast<const int4*>(Mi + base);
    const float4* Ac4 = reinterpret_cast<const float4*>(Ac + base);
    const float4* Bc4 = reinterpret_cast<const float4*>(Bc + base);

    float acc[TVC];
#pragma unroll
    for (int i = 0; i < TVC; ++i) acc[i] = 0.0f;

    for (int k8 = 0; k8 < 8; ++k8) {
        int4   m4 = Mi4[k8];
        float4 a4 = Ac4[k8];
        float4 b4 = Bc4[k8];
        int   mm[4] = {m4.x, m4.y, m4.z, m4.w};
        float AA[4] = {a4.x, a4.y, a4.z, a4.w};
        float BB[4] = {b4.x, b4.y, b4.z, b4.w};
        float c[4], s[4], cw[4], sw[4];
#pragma unroll
        for (int u = 0; u < 4; ++u) {
            float f0 = (float)((mm[u] * tv0) & 1023) * INV1024;   // phase in revolutions
            float fw = (float)mm[u] * INV1024;                    // step in revolutions
            c[u]  = __cosf(f0 * TWO_PI_F);
            s[u]  = __sinf(f0 * TWO_PI_F);
            cw[u] = __cosf(fw * TWO_PI_F);
            sw[u] = __sinf(fw * TWO_PI_F);
        }
#pragma unroll
        for (int i = 0; i < TVC; ++i) {
#pragma unroll
            for (int u = 0; u < 4; ++u) {
                acc[i] = fmaf(AA[u], c[u], fmaf(BB[u], s[u], acc[i]));
                float cn = fmaf(c[u], cw[u], -(s[u] * sw[u]));
                float sn = fmaf(s[u], cw[u],  (c[u] * sw[u]));
                c[u] = cn; s[u] = sn;
            }
        }
    }

    float* op = out + ((size_t)b * OUT_T + tv0) * DM + tid;
#pragma unroll
    for (int i = 0; i < TVC; ++i) {
        op[i * DM] = acc[i];
    }
}

extern "C" void kernel_launch(void* const* d_in, const int* in_sizes, int n_in,
                              void* d_out, int out_size, void* d_ws, size_t ws_size,
                              hipStream_t stream) {
    const float* x = (const float*)d_in[0];
    float* out = (float*)d_out;

    char* w = (char*)d_ws;
    const size_t NSIG = 8 * 256;
    const size_t coefBytes = NSIG * KSEL * sizeof(int);  // 256 KiB each
    int*   Mi   = (int*)(w);
    float* Ac   = (float*)(w + coefBytes);
    float* Bc   = (float*)(w + 2 * coefBytes);

    hipLaunchKernelGGL(fl_fft_topk_kernel, dim3(2048), dim3(256), 0, stream,
                       x, Mi, Ac, Bc);
    hipLaunchKernelGGL(fl_synth_kernel, dim3(OUT_T / TVC, 8), dim3(256), 0, stream,
                       Mi, Ac, Bc, out);
}

// Round 4
// 77.224 us; speedup vs baseline: 3.8928x; 1.1394x over previous
//
#include <hip/hip_runtime.h>
#include <math.h>

#define T_LEN 1024
#define PRED_LEN 256
#define OUT_T (T_LEN + PRED_LEN)
#define DM 256
#define KSEL 32
#define TVC 8

#define TWO_PI_F 6.2831853071795864769f
#define INV1024  0.0009765625f

// pad every 16 doubles by 1 to break power-of-2 bank strides
#define PADI(i) ((i) + ((i) >> 4))

// ---------------- Kernel T: fp64 twiddle table W[e] = exp(-2pi*i*e/1024) ----------------
// grid = 4 blocks x 256
__global__ void fl_twiddle_kernel(double* __restrict__ gwr, double* __restrict__ gwi) {
    int e = blockIdx.x * 256 + threadIdx.x;
    double ang = (double)e * (6.283185307179586476925286766559 / 1024.0);
    gwr[e] = cos(ang);
    gwi[e] = -sin(ang);
}

// ---------------- Kernel A: packed 2-column fp64 radix-4 FFT + top-32 ----------------
// grid = 1024 blocks (8*128 column-pairs), block = 256 threads
__global__ void __launch_bounds__(256)
fl_fft_topk_kernel(const float* __restrict__ x,
                   const double* __restrict__ gwr, const double* __restrict__ gwi,
                   int* __restrict__ Mi, float* __restrict__ Ac, float* __restrict__ Bc) {
    __shared__ double re[1088], im[1088];     // PADI(1023)=1086
    __shared__ double wre[1088], wim[1088];

    const int tid = threadIdx.x;
    // XCD-chunked swizzle (bijective over 1024): XCD k gets one contiguous chunk
    const int bid = blockIdx.x;
    const int sp  = ((bid & 7) << 7) | (bid >> 3);   // 0..1023
    const int b   = sp >> 7;
    const int d0  = (sp & 127) << 1;                 // even column; pair = (d0, d0+1)

    // stage twiddles global->LDS (coalesced, L3-resident)
    for (int q = 0; q < 4; ++q) {
        int e = tid + (q << 8);
        wre[PADI(e)] = gwr[e];
        wim[PADI(e)] = gwi[e];
    }
    // load two adjacent real columns as one complex series, base-4 digit-reversed
    for (int q = 0; q < 4; ++q) {
        int t = tid + (q << 8);
        unsigned r  = __brev((unsigned)t) >> 22;                    // 10-bit bit-reversal
        unsigned r4 = ((r & 0x155u) << 1) | ((r & 0x2AAu) >> 1);    // fix pairs -> base-4 reversal
        const float2 v = *reinterpret_cast<const float2*>(&x[((((b << 10) + t) << 8)) + d0]);
        int pr = PADI((int)r4);
        re[pr] = (double)v.x;
        im[pr] = (double)v.y;
    }
    __syncthreads();

    // radix-4 DIT, 5 stages, 256 butterflies/stage (1 per thread)
#pragma unroll
    for (int s = 0; s < 5; ++s) {
        const int h   = 1 << (2 * s);
        const int rsh = 2 * (4 - s);                 // W_N exponent scale = 4^(4-s)
        const int p   = tid & (h - 1);
        const int g   = tid >> (2 * s);
        const int base = (g << (2 * s + 2)) | p;
        const int P0 = PADI(base);
        const int P1 = PADI(base + h);
        const int P2 = PADI(base + 2 * h);
        const int P3 = PADI(base + 3 * h);
        const int e1 = p << rsh;                     // < 256
        const int e2 = e1 * 2;                       // < 512
        const int e3 = e1 * 3;                       // < 768

        double a0r = re[P0], a0i = im[P0];
        double a1r = re[P1], a1i = im[P1];
        double a2r = re[P2], a2i = im[P2];
        double a3r = re[P3], a3i = im[P3];
        double w1r = wre[PADI(e1)], w1i = wim[PADI(e1)];
        double w2r = wre[PADI(e2)], w2i = wim[PADI(e2)];
        double w3r = wre[PADI(e3)], w3i = wim[PADI(e3)];

        double b1r = a1r * w1r - a1i * w1i, b1i = a1r * w1i + a1i * w1r;
        double b2r = a2r * w2r - a2i * w2i, b2i = a2r * w2i + a2i * w2r;
        double b3r = a3r * w3r - a3i * w3i, b3i = a3r * w3i + a3i * w3r;

        double t0r = a0r + b2r, t0i = a0i + b2i;
        double t1r = a0r - b2r, t1i = a0i - b2i;
        double t2r = b1r + b3r, t2i = b1i + b3i;
        double t3r = b1r - b3r, t3i = b1i - b3i;

        re[P0] = t0r + t2r;  im[P0] = t0i + t2i;     // c0
        re[P2] = t0r - t2r;  im[P2] = t0i - t2i;     // c2
        re[P1] = t1r + t3i;  im[P1] = t1i - t3r;     // c1 = t1 - i*t3
        re[P3] = t1r - t3i;  im[P3] = t1i + t3r;     // c3 = t1 + i*t3
        __syncthreads();
    }

    // waves 2,3 done. Waves 0 and 1 each do top-k for one column of the pair.
    if (tid >= 128) return;
    const int lane = tid & 63;
    const int w    = tid >> 6;     // 0 -> column d0 (real part), 1 -> d0+1 (imag part)

    // unpack real-FFT spectra via conjugate symmetry; lane owns m = q*64+lane
    double v[8];
#pragma unroll
    for (int q = 0; q < 8; ++q) {
        int m = (q << 6) | lane;
        int n = (1024 - m) & 1023;
        double rm = re[PADI(m)], imv = im[PADI(m)];
        double rn = re[PADI(n)], inv = im[PADI(n)];
        double rr, ii;
        if (w == 0) { rr = 0.5 * (rm + rn);  ii = 0.5 * (imv - inv); }
        else        { rr = 0.5 * (imv + inv); ii = 0.5 * (rn - rm); }
        v[q] = rr * rr + ii * ii;
    }
    if (lane == 0) v[0] = -1.0;    // exclude m=0; m=512 excluded by range

    // 32 rounds of wave-wide shuffle argmax (tie -> lower m); no barriers
    int mysel = 0;
    for (int r = 0; r < KSEL; ++r) {
        double bv = v[0]; int bq = 0;
#pragma unroll
        for (int q = 1; q < 8; ++q) {
            if (v[q] > bv) { bv = v[q]; bq = q; }
        }
        int bi = (bq << 6) | lane;
#pragma unroll
        for (int off = 1; off < 64; off <<= 1) {
            double ov = __shfl_xor(bv, off);
            int    oi = __shfl_xor(bi, off);
            if (ov > bv || (ov == bv && oi < bi)) { bv = ov; bi = oi; }
        }
        if (lane == r) mysel = bi;
        if (lane == (bi & 63)) {               // owner removes it (static indexing)
            int wq = bi >> 6;
#pragma unroll
            for (int q = 0; q < 8; ++q) if (q == wq) v[q] = -1.0;
        }
    }

    if (lane < KSEL) {
        int m = mysel;
        int n = (1024 - m) & 1023;
        double rm = re[PADI(m)], imv = im[PADI(m)];
        double rn = re[PADI(n)], inv = im[PADI(n)];
        double rr, ii;
        if (w == 0) { rr = 0.5 * (rm + rn);  ii = 0.5 * (imv - inv); }
        else        { rr = 0.5 * (imv + inv); ii = 0.5 * (rn - rm); }
        int col   = (b << 8) + d0 + w;
        int basei = col * KSEL + lane;
        Mi[basei] = m;
        Ac[basei] = (float)( rr / 512.0);      //  2*Re/T
        Bc[basei] = (float)(-ii / 512.0);      // -2*Im/T
    }
}

// ---------------- Kernel B: synthesis, register-resident trig ----------------
// grid = (OUT_T/TVC, 8), block = 256 (thread = d); no LDS.
__global__ void __launch_bounds__(256)
fl_synth_kernel(const int* __restrict__ Mi, const float* __restrict__ Ac,
                const float* __restrict__ Bc, float* __restrict__ out) {
    const int tid = threadIdx.x;
    const int b   = blockIdx.y;
    const int tv0 = blockIdx.x * TVC;
    const int base = (((b << 8) + tid) << 5);  // (b*256+d)*32

    const int4*   Mi4 = reinterpret_cast<const int4*>(Mi + base);
    const float4* Ac4 = reinterpret_cast<const float4*>(Ac + base);
    const float4* Bc4 = reinterpret_cast<const float4*>(Bc + base);

    float acc[TVC];
#pragma unroll
    for (int i = 0; i < TVC; ++i) acc[i] = 0.0f;

    for (int k8 = 0; k8 < 8; ++k8) {
        int4   m4 = Mi4[k8];
        float4 a4 = Ac4[k8];
        float4 b4 = Bc4[k8];
        int   mm[4] = {m4.x, m4.y, m4.z, m4.w};
        float AA[4] = {a4.x, a4.y, a4.z, a4.w};
        float BB[4] = {b4.x, b4.y, b4.z, b4.w};
        float c[4], s[4], cw[4], sw[4];
#pragma unroll
        for (int u = 0; u < 4; ++u) {
            float f0 = (float)((mm[u] * tv0) & 1023) * INV1024;   // phase (revolutions)
            float fw = (float)mm[u] * INV1024;                    // step  (revolutions)
            c[u]  = __cosf(f0 * TWO_PI_F);
            s[u]  = __sinf(f0 * TWO_PI_F);
            cw[u] = __cosf(fw * TWO_PI_F);
            sw[u] = __sinf(fw * TWO_PI_F);
        }
#pragma unroll
        for (int i = 0; i < TVC; ++i) {
#pragma unroll
            for (int u = 0; u < 4; ++u) {
                acc[i] = fmaf(AA[u], c[u], fmaf(BB[u], s[u], acc[i]));
                float cn = fmaf(c[u], cw[u], -(s[u] * sw[u]));
                float sn = fmaf(s[u], cw[u],  (c[u] * sw[u]));
                c[u] = cn; s[u] = sn;
            }
        }
    }

    float* op = out + ((size_t)b * OUT_T + tv0) * DM + tid;
#pragma unroll
    for (int i = 0; i < TVC; ++i) {
        op[i * DM] = acc[i];
    }
}

extern "C" void kernel_launch(void* const* d_in, const int* in_sizes, int n_in,
                              void* d_out, int out_size, void* d_ws, size_t ws_size,
                              hipStream_t stream) {
    const float* x = (const float*)d_in[0];
    float* out = (float*)d_out;

    char* w = (char*)d_ws;
    const size_t NSIG = 8 * 256;
    const size_t coefBytes = NSIG * KSEL * sizeof(int);  // 256 KiB each
    int*    Mi  = (int*)(w);
    float*  Ac  = (float*)(w + coefBytes);
    float*  Bc  = (float*)(w + 2 * coefBytes);
    double* gwr = (double*)(w + 3 * coefBytes);
    double* gwi = (double*)(w + 3 * coefBytes + 1024 * sizeof(double));

    hipLaunchKernelGGL(fl_twiddle_kernel, dim3(4), dim3(256), 0, stream, gwr, gwi);
    hipLaunchKernelGGL(fl_fft_topk_kernel, dim3(1024), dim3(256), 0, stream,
                       x, gwr, gwi, Mi, Ac, Bc);
    hipLaunchKernelGGL(fl_synth_kernel, dim3(OUT_T / TVC, 8), dim3(256), 0, stream,
                       Mi, Ac, Bc, out);
}